// Round 7
// baseline (176.231 us; speedup 1.0000x reference)
//
#include <hip/hip_runtime.h>
#include <math.h>

#define DIM 192
#define OD  191          // output domain per axis
#define PLANE 36864      // 192*192
#define VOL 7077888      // 192^3
#define TW  14           // tile width  (w) -> 16-lane DPP row covers 16-wide halo
#define TH  32           // tile height (h): each thread owns rows ty and ty+16
#define CD  12           // d-planes per chunk
#define NBW 14           // ceil(191/14)
#define NBH 6            // ceil(191/32)
#define NCH 16           // 16*12 = 192 >= 191

typedef float    f4 __attribute__((ext_vector_type(4)));
typedef float    f2 __attribute__((ext_vector_type(2)));
typedef _Float16 h8 __attribute__((ext_vector_type(8)));
typedef _Float16 h4 __attribute__((ext_vector_type(4)));
typedef _Float16 h2 __attribute__((ext_vector_type(2)));

template<int CTRL>
__device__ __forceinline__ int dppi(int x) {
    // bound_ctrl=true: out-of-row / exec-off source reads as 0 (matches zero padding)
    return __builtin_amdgcn_update_dpp(0, x, CTRL, 0xF, 0xF, true);
}

union U8 { h8 v; int i[4]; };
union U2 { h2 v; int i; };

// Symmetric 3-tap w-window sum across a 16-lane DPP row:
//   out(lane) = in(lane-1) + in(lane) + in(lane+1), 0 outside the row.
__device__ __forceinline__ void wsum3(h8& a, h2& b) {
    U8 ua, s1, s2;
    ua.v = a;
    #pragma unroll
    for (int k = 0; k < 4; ++k) {
        s1.i[k] = dppi<0x101>(ua.i[k]);   // row_shl:1
        s2.i[k] = dppi<0x111>(ua.i[k]);   // row_shr:1
    }
    a = ua.v + s1.v + s2.v;
    U2 ub, t1, t2;
    ub.v = b;
    t1.i = dppi<0x101>(ub.i);
    t2.i = dppi<0x111>(ub.i);
    b = ub.v + t1.v + t2.v;
}

// Packed-f16 diff: c=center, cw=w+1, ch=h+1, cd=d+1 (all h4 {x,y,z,0}).
// Field order: va={hx,hy,hz,dx,dy,dz,wx,wy}, vb={wz,0}.
__device__ __forceinline__ void make_diff16(const h4 c, const h4 cw, const h4 ch, const h4 cd,
                                            h8& va, h2& vb) {
    const h4 dh = __builtin_elementwise_abs(ch - c);
    const h4 dd = __builtin_elementwise_abs(cd - c);
    const h4 dw = __builtin_elementwise_abs(cw - c);
    va = (h8){dh[0], dh[1], dh[2], dd[0], dd[1], dd[2], dw[0], dw[1]};
    vb = (h2){dw[2], (_Float16)0.f};
}

// Raw f32 load, NO dependent arithmetic in this iteration -> the vmcnt wait
// drifts into the NEXT iteration (keeps the software pipeline asynchronous).
__device__ __forceinline__ f4 ld3(const float* __restrict__ P, int idx, bool ok) {
    f4 r = (f4)0;
    if (ok) {
        r.x = P[idx];
        r.y = P[idx + VOL];
        r.z = P[idx + 2 * VOL];
    }
    return r;
}

// f32 -> packed f16 at STORE time: first use of the loaded value is one full
// iteration after the load was issued.
__device__ __forceinline__ h4 cvt16(const f4 v) {
    return (h4){(_Float16)v.x, (_Float16)v.y, (_Float16)v.z, (_Float16)0.f};
}

// Neo-hookean energy for TWO output points, computed as float2 vector math so
// the compiler can emit packed-f32 VOPP (v_pk_fma_f32 etc., full-rate on CDNA).
__device__ __forceinline__ f2 energy2(const h8 FAa, const h2 FBa,
                                      const h8 FAb, const h2 FBb) {
    const float inv27 = 1.f / 27.f;
#define MK2(i) ((f2){(float)FAa[i], (float)FAb[i]} * inv27)
    const f2 dydx = MK2(0), dxdx = MK2(1), dzdx = MK2(2);
    const f2 dydy = MK2(3), dxdy = MK2(4), dzdy = MK2(5);
    const f2 dydz = MK2(6), dxdz = MK2(7);
#undef MK2
    const f2 dzdz = (f2){(float)FBa[0], (float)FBb[0]} * inv27;
    const f2 a = dxdx + 1.f, e = dydy + 1.f, iN = dzdz + 1.f;
    const f2 J = a * (e * iN - dydz * dzdy)
               - dxdy * (dydx * iN - dydz * dzdx)
               + dxdz * (dydx * dzdy - e * dzdx);
    const f2 Tr = a * a + dxdy * dxdy + dxdz * dxdz
                + dydx * dydx + e * e + dydz * dydz
                + dzdx * dzdx + dzdy * dzdy + iN * iN;
    const f2 ex = (f2){__expf(1.f - J.x), __expf(1.f - J.y)};
    const f2 stretch = Tr * ex - 3.f;
    const f2 jm1 = J - 1.f;
    const f2 vol = jm1 * jm1;
    // mu=1,lam=5 -> U = (1/12)*stretch + (15/31)*vol (verified exact)
    return 0.0833333358f * stretch + 0.4838709677f * vol;
}

// Fused: diff -> separable 3x3x3 box mean (w: DPP, h: LDS 3-tap, z: register
// ring) -> neo-hookean energy -> mean reduction.
// Round-7: 32-row tile, 2 outputs per thread in h (rows ty, ty+16). Halves
// per-output barrier/loop/staging overhead; energy packed as f32x2. Pipeline
// structure from r6 (1-deep raw-f32 prefetch, cvt at store time, f16 LDS).
__global__ __launch_bounds__(256, 5)
void nh_fused_kernel(const float* __restrict__ P, float* __restrict__ out) {
    const int tid = threadIdx.x;
    const int tx  = tid & 15;        // lane within DPP row == w within halo
    const int ty  = tid >> 4;        // h row group (owns rows ty and ty+16)
    const int w0  = blockIdx.x * TW;
    const int h0  = blockIdx.y * TH;
    const int ds  = blockIdx.z * CD;
    const int de  = min(ds + CD, OD);

    __shared__ h4 sraw[2][35][18];   // raw y_pred (f16), rows h0-1..h0+33, cols w0-1..w0+15
    __shared__ h8 sW[2][34][16];     // w-summed diffs, double-buffered by t parity
    __shared__ h2 sWB[2][34][16];    // w-summed {Wd2, 0}
    __shared__ float wsum[4];

    // ---- loop-invariant geometry ----
    const int wp = w0 - 1 + tx;
    const bool wr = (wp >= 0) & (wp < DIM);
    const bool wd = (wp >= 0) & (wp < OD);

    // primary A: halo row ty; primary B: halo row ty+16
    const int hpA = h0 - 1 + ty;
    const int hpB = hpA + 16;
    const bool in_raw_A  = wr & (hpA >= 0) & (hpA < DIM);
    const bool in_raw_B  = wr & (hpB < DIM);          // hpB >= 15 always
    const bool in_diff_A = wd & (hpA >= 0) & (hpA < OD);
    const bool in_diff_B = wd & (hpB < OD);
    const int baseA = hpA * DIM + wp;
    const int baseB = hpB * DIM + wp;

    // leftover halo point: tids 0..47 -> rows 32..34 x cols 0..15 (tids 0..31
    // are exactly the pass-2 builders of rows 32,33); tids 48..82 -> col 16.
    int hh_l = 0, ww_l = 0;
    bool has_l = false;
    if (tid < 48)      { hh_l = 32 + (tid >> 4); ww_l = tid & 15; has_l = true; }
    else if (tid < 83) { hh_l = tid - 48;        ww_l = 16;       has_l = true; }
    const int hp_l = h0 - 1 + hh_l;
    const int wp_l = w0 - 1 + ww_l;
    const bool in_raw_l  = has_l & (hp_l >= 0) & (hp_l < DIM) & (wp_l >= 0) & (wp_l < DIM);
    const bool in_diff_l = (tid < 32) & (hp_l >= 0) & (hp_l < OD) & (wp_l >= 0) & (wp_l < OD);
    const int base_l = hp_l * DIM + wp_l;

    const bool validA = (tx < TW) && (w0 + tx < OD) && (h0 + ty < OD);
    const bool validB = (tx < TW) && (w0 + tx < OD) && (h0 + ty + 16 < OD);

    // z-rings for the two output rows
    h8 aA0 = (h8)0, aA1 = (h8)0, aA2 = (h8)0, aB0 = (h8)0, aB1 = (h8)0, aB2 = (h8)0;
    h2 bA0 = (h2)0, bA1 = (h2)0, bA2 = (h2)0, bB0 = (h2)0, bB1 = (h2)0, bB2 = (h2)0;
    f4 curA = (f4)0, curB = (f4)0, curL = (f4)0;     // raw f32 at plane t
    h4 prevA = (h4)0, prevB = (h4)0, prevL = (h4)0;  // f16 of plane t-1
    f2 acc = (f2)0;

    // preload plane t0 = ds-1 (zeros when t0 < 0)
    {
        const int t0 = ds - 1;
        if (t0 >= 0) {
            curA = ld3(P, t0 * PLANE + baseA, in_raw_A);
            curB = ld3(P, t0 * PLANE + baseB, in_raw_B);
            curL = ld3(P, t0 * PLANE + base_l, in_raw_l);
        }
    }

    for (int t = ds - 1; t <= de + 1; ++t) {
        const int cb = t & 1, pb = cb ^ 1;

        // (1) prefetch plane t+1 into regs; first use (cvt) is NEXT iteration
        f4 nxtA = (f4)0, nxtB = (f4)0, nxtL = (f4)0;
        {
            const int tn = t + 1;
            if ((tn < DIM) & (tn <= de + 1)) {       // wave-uniform
                nxtA = ld3(P, tn * PLANE + baseA, in_raw_A);
                nxtB = ld3(P, tn * PLANE + baseB, in_raw_B);
                nxtL = ld3(P, tn * PLANE + base_l, in_raw_l);
            }
        }

        // (2) convert plane t (loaded last iteration) to f16, stage to LDS
        const h4 c16A = cvt16(curA);
        const h4 c16B = cvt16(curB);
        sraw[cb][ty][tx]      = c16A;
        sraw[cb][ty + 16][tx] = c16B;
        h4 c16L = (h4)0;
        if (has_l) {
            c16L = cvt16(curL);
            sraw[cb][hh_l][ww_l] = c16L;
        }

        // (3) build w-summed diff plane p = t-1 into sW[cb]
        //     reads ONLY sraw[pb] (synced last iteration) + registers
        const bool built = (t >= ds) & (t - 1 >= 0);   // wave-uniform (t-1<OD always here)

        {   // pass 1a: rows 0..15
            h8 sa = (h8)0; h2 sb = (h2)0;
            if (built) {
                h8 va = (h8)0; h2 vb = (h2)0;
                if (in_diff_A) {
                    make_diff16(prevA,
                                sraw[pb][ty][tx + 1],
                                sraw[pb][ty + 1][tx],
                                c16A, va, vb);
                }
                wsum3(va, vb);
                sa = va; sb = vb;
            }
            sW[cb][ty][tx] = sa; sWB[cb][ty][tx] = sb;
        }
        {   // pass 1b: rows 16..31
            h8 sa = (h8)0; h2 sb = (h2)0;
            if (built) {
                h8 va = (h8)0; h2 vb = (h2)0;
                if (in_diff_B) {
                    make_diff16(prevB,
                                sraw[pb][ty + 16][tx + 1],
                                sraw[pb][ty + 17][tx],
                                c16B, va, vb);
                }
                wsum3(va, vb);
                sa = va; sb = vb;
            }
            sW[cb][ty + 16][tx] = sa; sWB[cb][ty + 16][tx] = sb;
        }
        if (tid < 32) {  // pass 2: rows 32,33 in ONE wave issue (two DPP rows)
            h8 sa = (h8)0; h2 sb = (h2)0;
            if (built) {
                h8 va = (h8)0; h2 vb = (h2)0;
                if (in_diff_l) {
                    make_diff16(prevL,
                                sraw[pb][hh_l][ww_l + 1],
                                sraw[pb][hh_l + 1][ww_l],
                                c16L, va, vb);
                }
                wsum3(va, vb);
                sa = va; sb = vb;
            }
            sW[cb][hh_l][ww_l] = sa; sWB[cb][hh_l][ww_l] = sb;
        }

        __syncthreads();   // the ONLY barrier per plane

        // (4) h-window 3-tap for both output rows, rotate z-rings, emit d = t-2
        aA0 = aA1; aA1 = aA2; bA0 = bA1; bA1 = bA2;
        aB0 = aB1; aB1 = aB2; bB0 = bB1; bB1 = bB2;
        {
            const int cc = (tx + 1) & 15;   // w-sum center lane; tx>=14 masked by valid
            aA2 = sW[cb][ty][cc]      + sW[cb][ty + 1][cc]  + sW[cb][ty + 2][cc];
            bA2 = sWB[cb][ty][cc]     + sWB[cb][ty + 1][cc] + sWB[cb][ty + 2][cc];
            aB2 = sW[cb][ty + 16][cc] + sW[cb][ty + 17][cc] + sW[cb][ty + 18][cc];
            bB2 = sWB[cb][ty + 16][cc]+ sWB[cb][ty + 17][cc]+ sWB[cb][ty + 18][cc];
        }

        const int d = t - 2;
        if (d >= ds && d < de) {
            const h8 FAa = aA0 + aA1 + aA2;
            const h2 FBa = bA0 + bA1 + bA2;
            const h8 FAb = aB0 + aB1 + aB2;
            const h2 FBb = bB0 + bB1 + bB2;
            const f2 u = energy2(FAa, FBa, FAb, FBb);
            acc.x += validA ? u.x : 0.f;
            acc.y += validB ? u.y : 0.f;
        }

        // rotate rings
        prevA = c16A; curA = nxtA;
        prevB = c16B; curB = nxtB;
        prevL = c16L; curL = nxtL;
    }

    // mean scaling (191^3)
    float accs = (acc.x + acc.y) * (1.f / 6967871.f);

    // wave reduce (64 lanes), then block reduce, one atomic per block
    #pragma unroll
    for (int off = 32; off > 0; off >>= 1) accs += __shfl_down(accs, off, 64);
    if ((tid & 63) == 0) wsum[tid >> 6] = accs;
    __syncthreads();
    if (tid == 0) {
        atomicAdd(out, wsum[0] + wsum[1] + wsum[2] + wsum[3]);
    }
}

extern "C" void kernel_launch(void* const* d_in, const int* in_sizes, int n_in,
                              void* d_out, int out_size, void* d_ws, size_t ws_size,
                              hipStream_t stream) {
    const float* y_pred = (const float*)d_in[0];
    float* out = (float*)d_out;

    // d_out is poisoned 0xAA before every timed launch — zero it (graph-capturable).
    hipMemsetAsync(out, 0, sizeof(float), stream);

    dim3 grid(NBW, NBH, NCH);
    nh_fused_kernel<<<grid, 256, 0, stream>>>(y_pred, out);
}

// Round 8
// 174.181 us; speedup vs baseline: 1.0118x; 1.0118x over previous
//
#include <hip/hip_runtime.h>
#include <math.h>

#define DIM 192
#define OD  191          // output domain per axis
#define PLANE 36864      // 192*192
#define VOL 7077888      // 192^3
#define TW  14           // tile width  (w)  -> 16-lane DPP row covers 16-wide halo
#define TH  16           // tile height (h)
#define CD  16           // d-planes per chunk
#define NBW 14           // ceil(191/14)
#define NBH 12           // ceil(191/16)
#define NCH 12           // 12*16 = 192 >= 191

typedef float    f4 __attribute__((ext_vector_type(4)));
typedef float    f2 __attribute__((ext_vector_type(2)));
typedef _Float16 h8 __attribute__((ext_vector_type(8)));
typedef _Float16 h4 __attribute__((ext_vector_type(4)));
typedef _Float16 h2 __attribute__((ext_vector_type(2)));

template<int CTRL>
__device__ __forceinline__ int dppi(int x) {
    // bound_ctrl=true: out-of-row / exec-off source reads as 0 (matches zero padding)
    return __builtin_amdgcn_update_dpp(0, x, CTRL, 0xF, 0xF, true);
}

union U8 { h8 v; int i[4]; };
union U2 { h2 v; int i; };

// Symmetric 3-tap w-window sum across a 16-lane DPP row:
//   out(lane) = in(lane-1) + in(lane) + in(lane+1), 0 outside the row.
__device__ __forceinline__ void wsum3(h8& a, h2& b) {
    U8 ua, s1, s2;
    ua.v = a;
    #pragma unroll
    for (int k = 0; k < 4; ++k) {
        s1.i[k] = dppi<0x101>(ua.i[k]);   // row_shl:1
        s2.i[k] = dppi<0x111>(ua.i[k]);   // row_shr:1
    }
    a = ua.v + s1.v + s2.v;
    U2 ub, t1, t2;
    ub.v = b;
    t1.i = dppi<0x101>(ub.i);
    t2.i = dppi<0x111>(ub.i);
    b = ub.v + t1.v + t2.v;
}

// Packed-f16 diff: c=center, cw=w+1, ch=h+1, cd=d+1 (all h4 {x,y,z,0}).
// Field order: va={hx,hy,hz,dx,dy,dz,wx,wy}, vb={wz,0}.
__device__ __forceinline__ void make_diff16(const h4 c, const h4 cw, const h4 ch, const h4 cd,
                                            h8& va, h2& vb) {
    const h4 dh = __builtin_elementwise_abs(ch - c);
    const h4 dd = __builtin_elementwise_abs(cd - c);
    const h4 dw = __builtin_elementwise_abs(cw - c);
    va = (h8){dh[0], dh[1], dh[2], dd[0], dd[1], dd[2], dw[0], dw[1]};
    vb = (h2){dw[2], (_Float16)0.f};
}

// Raw f32 load, NO dependent arithmetic in this iteration -> the vmcnt wait
// drifts into the NEXT iteration (keeps the software pipeline asynchronous).
__device__ __forceinline__ f4 ld3(const float* __restrict__ P, int idx, bool ok) {
    f4 r = (f4)0;
    if (ok) {
        r.x = P[idx];
        r.y = P[idx + VOL];
        r.z = P[idx + 2 * VOL];
    }
    return r;
}

// f32 -> packed f16 at STORE time: first use of the loaded value is one full
// iteration after the load was issued.
__device__ __forceinline__ h4 cvt16(const f4 v) {
    return (h4){(_Float16)v.x, (_Float16)v.y, (_Float16)v.z, (_Float16)0.f};
}

// Neo-hookean energy for TWO output points (planes d and d+1 of the same
// (h,w) column), as float2 vector math -> packed-f32 VOPP (v_pk_fma_f32 etc).
__device__ __forceinline__ f2 energy2(const h8 FAa, const h2 FBa,
                                      const h8 FAb, const h2 FBb) {
    const float inv27 = 1.f / 27.f;
#define MK2(i) ((f2){(float)FAa[i], (float)FAb[i]} * inv27)
    const f2 dydx = MK2(0), dxdx = MK2(1), dzdx = MK2(2);
    const f2 dydy = MK2(3), dxdy = MK2(4), dzdy = MK2(5);
    const f2 dydz = MK2(6), dxdz = MK2(7);
#undef MK2
    const f2 dzdz = (f2){(float)FBa[0], (float)FBb[0]} * inv27;
    const f2 a = dxdx + 1.f, e = dydy + 1.f, iN = dzdz + 1.f;
    const f2 J = a * (e * iN - dydz * dzdy)
               - dxdy * (dydx * iN - dydz * dzdx)
               + dxdz * (dydx * dzdy - e * dzdx);
    const f2 Tr = a * a + dxdy * dxdy + dxdz * dxdz
                + dydx * dydx + e * e + dydz * dydz
                + dzdx * dzdx + dzdy * dzdy + iN * iN;
    const f2 ex = (f2){__expf(1.f - J.x), __expf(1.f - J.y)};
    const f2 stretch = Tr * ex - 3.f;
    const f2 jm1 = J - 1.f;
    const f2 vol = jm1 * jm1;
    // mu=1,lam=5 -> U = (1/12)*stretch + (15/31)*vol (verified exact)
    return 0.0833333358f * stretch + 0.4838709677f * vol;
}

// Scalar energy (tail plane of an odd-length chunk).
__device__ __forceinline__ float energy1(const h8 FA, const h2 FB) {
    const float inv27 = 1.f / 27.f;
    const float dydx = (float)FA[0] * inv27, dxdx = (float)FA[1] * inv27, dzdx = (float)FA[2] * inv27;
    const float dydy = (float)FA[3] * inv27, dxdy = (float)FA[4] * inv27, dzdy = (float)FA[5] * inv27;
    const float dydz = (float)FA[6] * inv27, dxdz = (float)FA[7] * inv27, dzdz = (float)FB[0] * inv27;
    const float a = dxdx + 1.f, e = dydy + 1.f, iN = dzdz + 1.f;
    const float J = a * (e * iN - dydz * dzdy)
                  - dxdy * (dydx * iN - dydz * dzdx)
                  + dxdz * (dydx * dzdy - e * dzdx);
    const float Tr = a * a + dxdy * dxdy + dxdz * dxdz
                   + dydx * dydx + e * e + dydz * dydz
                   + dzdx * dzdx + dzdy * dzdy + iN * iN;
    const float stretch = Tr * __expf(1.f - J) - 3.f;
    const float vol = (J - 1.f) * (J - 1.f);
    return 0.0833333358f * stretch + 0.4838709677f * vol;
}

// Fused: diff -> separable 3x3x3 box mean (w: DPP, h: LDS 3-tap, z: register
// ring) -> neo-hookean energy -> mean reduction.
// Round-8: r6 structure (best stall: 8 blocks/CU, 1 barrier/plane, 1-deep
// raw-f32 prefetch, cvt at store) + z-PAIRED packed-f32 energy: bank plane
// d's filtered fields, evaluate energy for {d,d+1} together as float2
// (r7 proved the packing saves ~8us issue; this time with zero LDS cost).
__global__ __launch_bounds__(256, 8)
void nh_fused_kernel(const float* __restrict__ P, float* __restrict__ out) {
    const int tid = threadIdx.x;
    const int tx  = tid & 15;        // lane within DPP row == w within halo
    const int ty  = tid >> 4;        // h within tile
    const int w0  = blockIdx.x * TW;
    const int h0  = blockIdx.y * TH;
    const int ds  = blockIdx.z * CD;
    const int de  = min(ds + CD, OD);

    __shared__ h4 sraw[2][19][18];   // raw y_pred (f16 packed), rows h0-1..h0+17, cols w0-1..w0+15
    __shared__ h8 sW[2][18][16];     // w-summed diffs, double-buffered by t parity
    __shared__ h2 sWB[2][18][16];    // w-summed {Wd2, 0}
    __shared__ float wsum[4];

    // ---- loop-invariant geometry ----
    // primary halo point (ty, tx): staged + built by every thread
    const int hp_p = h0 - 1 + ty;
    const int wp_p = w0 - 1 + tx;
    const bool in_raw_p  = (hp_p >= 0) & (hp_p < DIM) & (wp_p >= 0) & (wp_p < DIM);
    const bool in_diff_p = (hp_p >= 0) & (hp_p < OD)  & (wp_p >= 0) & (wp_p < OD);
    const int base_p = hp_p * DIM + wp_p;

    // leftover halo point: tids 0..47 -> rows 16..18 x cols 0..15 (so pass-2
    // threads 0..31 own exactly the rows-16/17 points they build);
    // tids 48..66 -> col 16, rows 0..18.
    int hh_l, ww_l;
    if (tid < 48) { hh_l = 16 + (tid >> 4); ww_l = tid & 15; }
    else          { hh_l = tid - 48;        ww_l = 16; }
    const bool has_l = (tid < 67);
    const int hp_l = h0 - 1 + hh_l;
    const int wp_l = w0 - 1 + ww_l;
    const bool in_raw_l  = has_l & (hp_l >= 0) & (hp_l < DIM) & (wp_l >= 0) & (wp_l < DIM);
    const bool in_diff_l = (tid < 32) & (hp_l >= 0) & (hp_l < OD) & (wp_l >= 0) & (wp_l < OD);
    const int base_l = hp_l * DIM + wp_l;

    const bool valid = (tx < TW) && (w0 + tx < OD) && (h0 + ty < OD);

    h8 a0 = (h8)0, a1 = (h8)0, a2 = (h8)0;
    h2 b0 = (h2)0, b1 = (h2)0, b2 = (h2)0;
    f4 cur_p = (f4)0, cur_l = (f4)0;        // raw f32 at plane t (loaded last iteration)
    h4 prev16_p = (h4)0, prev16_l = (h4)0;  // f16 of plane t-1 (diff center)
    h8 pFA = (h8)0;                          // banked filtered fields of plane d (pair slot)
    h2 pFB = (h2)0;
    bool have = false;                       // wave-uniform pair-parity toggle
    f2 acc = (f2)0;

    // preload plane t0 = ds-1 (zeros when t0 < 0)
    {
        const int t0 = ds - 1;
        if (t0 >= 0) {
            cur_p = ld3(P, t0 * PLANE + base_p, in_raw_p);
            cur_l = ld3(P, t0 * PLANE + base_l, in_raw_l);
        }
    }

    for (int t = ds - 1; t <= de + 1; ++t) {
        const int cb = t & 1, pb = cb ^ 1;

        // (1) prefetch plane t+1 into regs; first use (cvt) is NEXT iteration,
        //     so the ~900cy HBM latency hides under this plane's work
        f4 nxt_p = (f4)0, nxt_l = (f4)0;
        {
            const int tn = t + 1;
            if ((tn < DIM) & (tn <= de + 1)) {       // wave-uniform
                nxt_p = ld3(P, tn * PLANE + base_p, in_raw_p);
                nxt_l = ld3(P, tn * PLANE + base_l, in_raw_l);
            }
        }

        // (2) convert plane t (loaded last iteration) to f16, stage to LDS
        const h4 cur16_p = cvt16(cur_p);
        sraw[cb][ty][tx] = cur16_p;
        h4 cur16_l = (h4)0;
        if (has_l) {
            cur16_l = cvt16(cur_l);
            sraw[cb][hh_l][ww_l] = cur16_l;
        }

        // (3) build w-summed diff plane p = t-1 into sW[cb]
        //     reads ONLY sraw[pb] (synced last iteration) + registers
        const bool built = (t >= ds) & (t - 1 >= 0) & (t - 1 < OD);   // wave-uniform

        {   // pass 1: rows 0..15 (all threads)
            h8 sa = (h8)0; h2 sb = (h2)0;
            if (built) {
                h8 va = (h8)0; h2 vb = (h2)0;
                if (in_diff_p) {
                    make_diff16(prev16_p,
                                sraw[pb][ty][tx + 1],     // (p, hp, wp+1)
                                sraw[pb][ty + 1][tx],     // (p, hp+1, wp)
                                cur16_p, va, vb);
                }
                wsum3(va, vb);                            // all lanes participate
                sa = va; sb = vb;
            }
            sW[cb][ty][tx] = sa; sWB[cb][ty][tx] = sb;
        }
        if (tid < 32) {  // pass 2: rows 16,17 in ONE wave issue (two DPP rows)
            h8 sa = (h8)0; h2 sb = (h2)0;
            if (built) {
                h8 va = (h8)0; h2 vb = (h2)0;
                if (in_diff_l) {
                    make_diff16(prev16_l,
                                sraw[pb][hh_l][ww_l + 1],
                                sraw[pb][hh_l + 1][ww_l],
                                cur16_l, va, vb);
                }
                wsum3(va, vb);
                sa = va; sb = vb;
            }
            sW[cb][hh_l][ww_l] = sa; sWB[cb][hh_l][ww_l] = sb;
        }

        __syncthreads();   // the ONLY barrier per plane

        // (4) h-window 3-tap, rotate z-ring, emit d = t-2
        a0 = a1; a1 = a2; b0 = b1; b1 = b2;
        {
            const int cc = (tx + 1) & 15;   // w-sum center lane; tx>=14 masked by valid
            a2 = sW[cb][ty][cc] + sW[cb][ty + 1][cc] + sW[cb][ty + 2][cc];
            b2 = sWB[cb][ty][cc] + sWB[cb][ty + 1][cc] + sWB[cb][ty + 2][cc];
        }

        const int d = t - 2;
        if (d >= ds && d < de) {            // wave-uniform
            const h8 FA = a0 + a1 + a2;
            const h2 FB = b0 + b1 + b2;
            if (!have) {                    // bank plane d, defer energy
                pFA = FA; pFB = FB; have = true;
            } else {                        // evaluate {d-1, d} together, packed f32
                const f2 u = energy2(pFA, pFB, FA, FB);
                if (valid) { acc.x += u.x; acc.y += u.y; }
                have = false;
            }
        }

        // rotate rings
        prev16_p = cur16_p; cur_p = nxt_p;
        prev16_l = cur16_l; cur_l = nxt_l;
    }

    // odd-length chunk tail (last chunk has 15 planes): flush banked plane
    float accs = acc.x + acc.y;
    if (have && valid) accs += energy1(pFA, pFB);

    // mean scaling (191^3)
    accs *= (1.f / 6967871.f);

    // wave reduce (64 lanes), then block reduce, one atomic per block
    #pragma unroll
    for (int off = 32; off > 0; off >>= 1) accs += __shfl_down(accs, off, 64);
    if ((tid & 63) == 0) wsum[tid >> 6] = accs;
    __syncthreads();
    if (tid == 0) {
        atomicAdd(out, wsum[0] + wsum[1] + wsum[2] + wsum[3]);
    }
}

extern "C" void kernel_launch(void* const* d_in, const int* in_sizes, int n_in,
                              void* d_out, int out_size, void* d_ws, size_t ws_size,
                              hipStream_t stream) {
    const float* y_pred = (const float*)d_in[0];
    float* out = (float*)d_out;

    // d_out is poisoned 0xAA before every timed launch — zero it (graph-capturable).
    hipMemsetAsync(out, 0, sizeof(float), stream);

    dim3 grid(NBW, NBH, NCH);
    nh_fused_kernel<<<grid, 256, 0, stream>>>(y_pred, out);
}

// Round 9
// 174.081 us; speedup vs baseline: 1.0124x; 1.0006x over previous
//
#include <hip/hip_runtime.h>
#include <math.h>

#define DIM 192
#define OD  191          // output domain per axis
#define PLANE 36864      // 192*192
#define VOL 7077888      // 192^3
#define TW  14           // tile width  (w)  -> 16-lane DPP row covers 16-wide halo
#define TH  16           // tile height (h)
#define CD  16           // d-planes per chunk
#define NBW 14           // ceil(191/14)
#define NBH 12           // ceil(191/16)
#define NCH 12           // 12*16 = 192 >= 191

typedef float    f4 __attribute__((ext_vector_type(4)));
typedef _Float16 h8 __attribute__((ext_vector_type(8)));
typedef _Float16 h4 __attribute__((ext_vector_type(4)));
typedef _Float16 h2 __attribute__((ext_vector_type(2)));

template<int CTRL>
__device__ __forceinline__ int dppi(int x) {
    // bound_ctrl=true: out-of-row / exec-off source reads as 0 (matches zero padding)
    return __builtin_amdgcn_update_dpp(0, x, CTRL, 0xF, 0xF, true);
}

union U8 { h8 v; int i[4]; };
union U2 { h2 v; int i; };

// Symmetric 3-tap w-window sum across a 16-lane DPP row:
//   out(lane) = in(lane-1) + in(lane) + in(lane+1), 0 outside the row.
__device__ __forceinline__ void wsum3(h8& a, h2& b) {
    U8 ua, s1, s2;
    ua.v = a;
    #pragma unroll
    for (int k = 0; k < 4; ++k) {
        s1.i[k] = dppi<0x101>(ua.i[k]);   // row_shl:1
        s2.i[k] = dppi<0x111>(ua.i[k]);   // row_shr:1
    }
    a = ua.v + s1.v + s2.v;
    U2 ub, t1, t2;
    ub.v = b;
    t1.i = dppi<0x101>(ub.i);
    t2.i = dppi<0x111>(ub.i);
    b = ub.v + t1.v + t2.v;
}

// Packed-f16 diff: c=center, cw=w+1, ch=h+1, cd=d+1 (all h4 {x,y,z,0}).
// Field order: va={hx,hy,hz,dx,dy,dz,wx,wy}, vb={wz,0}.
__device__ __forceinline__ void make_diff16(const h4 c, const h4 cw, const h4 ch, const h4 cd,
                                            h8& va, h2& vb) {
    const h4 dh = __builtin_elementwise_abs(ch - c);
    const h4 dd = __builtin_elementwise_abs(cd - c);
    const h4 dw = __builtin_elementwise_abs(cw - c);
    va = (h8){dh[0], dh[1], dh[2], dd[0], dd[1], dd[2], dw[0], dw[1]};
    vb = (h2){dw[2], (_Float16)0.f};
}

// Raw f32 load, NO dependent arithmetic in this iteration -> the vmcnt wait
// drifts into the NEXT iteration (keeps the software pipeline asynchronous).
__device__ __forceinline__ f4 ld3(const float* __restrict__ P, int idx, bool ok) {
    f4 r = (f4)0;
    if (ok) {
        r.x = P[idx];
        r.y = P[idx + VOL];
        r.z = P[idx + 2 * VOL];
    }
    return r;
}

// f32 -> packed f16 at STORE time: first use of the loaded value is one full
// iteration after the load was issued.
__device__ __forceinline__ h4 cvt16(const f4 v) {
    return (h4){(_Float16)v.x, (_Float16)v.y, (_Float16)v.z, (_Float16)0.f};
}

// Fused: diff -> separable 3x3x3 box mean (w: DPP, h: LDS 3-tap, z: register
// ring) -> neo-hookean energy -> mean reduction.
// Round-9: r6 structure + lgkm-only barrier. __syncthreads() compiles to a
// FULL `s_waitcnt vmcnt(0) lgkmcnt(0)` before s_barrier (m97 evidence), which
// drained our register-destined prefetch loads every plane -- the software
// pipeline never actually crossed the barrier. The barrier only needs to
// order LDS traffic, so: `s_waitcnt lgkmcnt(0)` + raw s_barrier; the global
// loads stay in flight and their vmcnt wait lands at the cvt next iteration.
__global__ __launch_bounds__(256, 8)
void nh_fused_kernel(const float* __restrict__ P, float* __restrict__ out) {
    const int tid = threadIdx.x;
    const int tx  = tid & 15;        // lane within DPP row == w within halo
    const int ty  = tid >> 4;        // h within tile
    const int w0  = blockIdx.x * TW;
    const int h0  = blockIdx.y * TH;
    const int ds  = blockIdx.z * CD;
    const int de  = min(ds + CD, OD);

    __shared__ h4 sraw[2][19][18];   // raw y_pred (f16 packed), rows h0-1..h0+17, cols w0-1..w0+15
    __shared__ h8 sW[2][18][16];     // w-summed diffs, double-buffered by t parity
    __shared__ h2 sWB[2][18][16];    // w-summed {Wd2, 0}
    __shared__ float wsum[4];

    // ---- loop-invariant geometry ----
    // primary halo point (ty, tx): staged + built by every thread
    const int hp_p = h0 - 1 + ty;
    const int wp_p = w0 - 1 + tx;
    const bool in_raw_p  = (hp_p >= 0) & (hp_p < DIM) & (wp_p >= 0) & (wp_p < DIM);
    const bool in_diff_p = (hp_p >= 0) & (hp_p < OD)  & (wp_p >= 0) & (wp_p < OD);
    const int base_p = hp_p * DIM + wp_p;

    // leftover halo point: tids 0..47 -> rows 16..18 x cols 0..15 (so pass-2
    // threads 0..31 own exactly the rows-16/17 points they build);
    // tids 48..66 -> col 16, rows 0..18.
    int hh_l, ww_l;
    if (tid < 48) { hh_l = 16 + (tid >> 4); ww_l = tid & 15; }
    else          { hh_l = tid - 48;        ww_l = 16; }
    const bool has_l = (tid < 67);
    const int hp_l = h0 - 1 + hh_l;
    const int wp_l = w0 - 1 + ww_l;
    const bool in_raw_l  = has_l & (hp_l >= 0) & (hp_l < DIM) & (wp_l >= 0) & (wp_l < DIM);
    const bool in_diff_l = (tid < 32) & (hp_l >= 0) & (hp_l < OD) & (wp_l >= 0) & (wp_l < OD);
    const int base_l = hp_l * DIM + wp_l;

    const bool valid = (tx < TW) && (w0 + tx < OD) && (h0 + ty < OD);

    h8 a0 = (h8)0, a1 = (h8)0, a2 = (h8)0;
    h2 b0 = (h2)0, b1 = (h2)0, b2 = (h2)0;
    f4 cur_p = (f4)0, cur_l = (f4)0;        // raw f32 at plane t (loaded last iteration)
    h4 prev16_p = (h4)0, prev16_l = (h4)0;  // f16 of plane t-1 (diff center)
    float acc = 0.f;

    // preload plane t0 = ds-1 (zeros when t0 < 0)
    {
        const int t0 = ds - 1;
        if (t0 >= 0) {
            cur_p = ld3(P, t0 * PLANE + base_p, in_raw_p);
            cur_l = ld3(P, t0 * PLANE + base_l, in_raw_l);
        }
    }

    for (int t = ds - 1; t <= de + 1; ++t) {
        const int cb = t & 1, pb = cb ^ 1;

        // (1) prefetch plane t+1 into regs; first use (cvt) is NEXT iteration,
        //     and with the lgkm-only barrier the load now genuinely stays in
        //     flight across the barrier -> HBM latency hides under a full plane
        f4 nxt_p = (f4)0, nxt_l = (f4)0;
        {
            const int tn = t + 1;
            if ((tn < DIM) & (tn <= de + 1)) {       // wave-uniform
                nxt_p = ld3(P, tn * PLANE + base_p, in_raw_p);
                nxt_l = ld3(P, tn * PLANE + base_l, in_raw_l);
            }
        }

        // (2) convert plane t (loaded last iteration) to f16, stage to LDS
        const h4 cur16_p = cvt16(cur_p);
        sraw[cb][ty][tx] = cur16_p;
        h4 cur16_l = (h4)0;
        if (has_l) {
            cur16_l = cvt16(cur_l);
            sraw[cb][hh_l][ww_l] = cur16_l;
        }

        // (3) build w-summed diff plane p = t-1 into sW[cb]
        //     reads ONLY sraw[pb] (synced last iteration) + registers
        const bool built = (t >= ds) & (t - 1 >= 0) & (t - 1 < OD);   // wave-uniform

        {   // pass 1: rows 0..15 (all threads)
            h8 sa = (h8)0; h2 sb = (h2)0;
            if (built) {
                h8 va = (h8)0; h2 vb = (h2)0;
                if (in_diff_p) {
                    make_diff16(prev16_p,
                                sraw[pb][ty][tx + 1],     // (p, hp, wp+1)
                                sraw[pb][ty + 1][tx],     // (p, hp+1, wp)
                                cur16_p, va, vb);
                }
                wsum3(va, vb);                            // all lanes participate
                sa = va; sb = vb;
            }
            sW[cb][ty][tx] = sa; sWB[cb][ty][tx] = sb;
        }
        if (tid < 32) {  // pass 2: rows 16,17 in ONE wave issue (two DPP rows)
            h8 sa = (h8)0; h2 sb = (h2)0;
            if (built) {
                h8 va = (h8)0; h2 vb = (h2)0;
                if (in_diff_l) {
                    make_diff16(prev16_l,
                                sraw[pb][hh_l][ww_l + 1],
                                sraw[pb][hh_l + 1][ww_l],
                                cur16_l, va, vb);
                }
                wsum3(va, vb);
                sa = va; sb = vb;
            }
            sW[cb][hh_l][ww_l] = sa; sWB[cb][hh_l][ww_l] = sb;
        }

        // ---- lgkm-only barrier: order LDS writes vs reads WITHOUT draining
        //      the register-destined global prefetch (vmcnt stays in flight;
        //      the compiler puts the vmcnt wait at the cvt next iteration).
        asm volatile("s_waitcnt lgkmcnt(0)" ::: "memory");
        __builtin_amdgcn_s_barrier();

        // (4) h-window 3-tap, rotate z-ring, emit d = t-2
        a0 = a1; a1 = a2; b0 = b1; b1 = b2;
        {
            const int cc = (tx + 1) & 15;   // w-sum center lane; tx>=14 masked by valid
            a2 = sW[cb][ty][cc] + sW[cb][ty + 1][cc] + sW[cb][ty + 2][cc];
            b2 = sWB[cb][ty][cc] + sWB[cb][ty + 1][cc] + sWB[cb][ty + 2][cc];
        }

        const int d = t - 2;
        if (valid && d >= ds && d < de) {
            const h8 FA = a0 + a1 + a2;
            const h2 FB = b0 + b1 + b2;
            const float inv27 = 1.f / 27.f;
            const float dydx = (float)FA[0] * inv27, dxdx = (float)FA[1] * inv27, dzdx = (float)FA[2] * inv27;
            const float dydy = (float)FA[3] * inv27, dxdy = (float)FA[4] * inv27, dzdy = (float)FA[5] * inv27;
            const float dydz = (float)FA[6] * inv27, dxdz = (float)FA[7] * inv27, dzdz = (float)FB[0] * inv27;
            const float a = dxdx + 1.f, e = dydy + 1.f, iN = dzdz + 1.f;
            const float J = a * (e * iN - dydz * dzdy)
                          - dxdy * (dydx * iN - dydz * dzdx)
                          + dxdz * (dydx * dzdy - e * dzdx);
            const float Tr = a * a + dxdy * dxdy + dxdz * dxdz
                           + dydx * dydx + e * e + dydz * dydz
                           + dzdx * dzdx + dzdy * dzdy + iN * iN;
            const float stretch = Tr * __expf(1.f - J) - 3.f;
            const float vol = (J - 1.f) * (J - 1.f);
            // mu=1,lam=5 -> U = (1/12)*stretch + (15/31)*vol (verified exact)
            acc += 0.0833333358f * stretch + 0.4838709677f * vol;
        }

        // rotate rings
        prev16_p = cur16_p; cur_p = nxt_p;
        prev16_l = cur16_l; cur_l = nxt_l;
    }

    // mean scaling (191^3)
    acc *= (1.f / 6967871.f);

    // wave reduce (64 lanes), then block reduce, one atomic per block
    #pragma unroll
    for (int off = 32; off > 0; off >>= 1) acc += __shfl_down(acc, off, 64);
    if ((tid & 63) == 0) wsum[tid >> 6] = acc;
    __syncthreads();
    if (tid == 0) {
        atomicAdd(out, wsum[0] + wsum[1] + wsum[2] + wsum[3]);
    }
}

extern "C" void kernel_launch(void* const* d_in, const int* in_sizes, int n_in,
                              void* d_out, int out_size, void* d_ws, size_t ws_size,
                              hipStream_t stream) {
    const float* y_pred = (const float*)d_in[0];
    float* out = (float*)d_out;

    // d_out is poisoned 0xAA before every timed launch — zero it (graph-capturable).
    hipMemsetAsync(out, 0, sizeof(float), stream);

    dim3 grid(NBW, NBH, NCH);
    nh_fused_kernel<<<grid, 256, 0, stream>>>(y_pred, out);
}